// Round 5
// baseline (473.740 us; speedup 1.0000x reference)
//
#include <hip/hip_runtime.h>
#include <math.h>

#define N 8192
#define D 512
#define KSEL 5
#define TEMP_INV 10.0f
#define MARGIN 0.012f
#define CCAP 48
#define APAD 40   // main-loop LDS pitch in shorts (proven R2-R4)
#define CPITCH 136  // epilogue C-stage pitch in shorts: 272 B = 17*16 (b128-aligned)

using short8 = __attribute__((ext_vector_type(8))) short;
using floatx4 = __attribute__((ext_vector_type(4))) float;

// Lexicographic top-5 insert: (value desc, index asc) — matches lax.top_k.
#define INS(TV, TIX, RI, VV, JJ)                                                     \
  {                                                                                  \
    const float _v = (VV);                                                           \
    const int _j = (JJ);                                                             \
    const bool _b4 = (_v > TV[RI][4]) || (_v == TV[RI][4] && _j < TIX[RI][4]);       \
    if (_b4) {                                                                       \
      const bool _b0 = (_v > TV[RI][0]) || (_v == TV[RI][0] && _j < TIX[RI][0]);     \
      const bool _b1 = (_v > TV[RI][1]) || (_v == TV[RI][1] && _j < TIX[RI][1]);     \
      const bool _b2 = (_v > TV[RI][2]) || (_v == TV[RI][2] && _j < TIX[RI][2]);     \
      const bool _b3 = (_v > TV[RI][3]) || (_v == TV[RI][3] && _j < TIX[RI][3]);     \
      TV[RI][4] = _b3 ? TV[RI][3] : _v;                                              \
      TIX[RI][4] = _b3 ? TIX[RI][3] : _j;                                            \
      TV[RI][3] = _b2 ? TV[RI][2] : (_b3 ? _v : TV[RI][3]);                          \
      TIX[RI][3] = _b2 ? TIX[RI][2] : (_b3 ? _j : TIX[RI][3]);                       \
      TV[RI][2] = _b1 ? TV[RI][1] : (_b2 ? _v : TV[RI][2]);                          \
      TIX[RI][2] = _b1 ? TIX[RI][1] : (_b2 ? _j : TIX[RI][2]);                       \
      TV[RI][1] = _b0 ? TV[RI][0] : (_b1 ? _v : TV[RI][1]);                          \
      TIX[RI][1] = _b0 ? TIX[RI][0] : (_b1 ? _j : TIX[RI][1]);                       \
      TV[RI][0] = _b0 ? _v : TV[RI][0];                                              \
      TIX[RI][0] = _b0 ? _j : TIX[RI][0];                                            \
    }                                                                                \
  }

__device__ inline unsigned short f2b(float f) {  // fp32 -> bf16 RNE
    unsigned int u = __float_as_uint(f);
    unsigned int r = (u + 0x7FFFu + ((u >> 16) & 1u)) >> 16;
    return (unsigned short)r;
}
__device__ inline float b2f(unsigned short u) {
    return __uint_as_float(((unsigned int)u) << 16);
}

// ---------------- Kernel 1: norms + bf16 normalized rows -----------------
__global__ __launch_bounds__(64) void prep_kernel(const float* __restrict__ X,
                                                  unsigned short* __restrict__ Xb,
                                                  float* __restrict__ inv) {
    const int row = blockIdx.x;
    const int t = threadIdx.x;
    const float4* xr = (const float4*)(X + (size_t)row * D);
    const float4 a = xr[t];
    const float4 b = xr[t + 64];
    float ss = a.x * a.x + a.y * a.y + a.z * a.z + a.w * a.w +
               b.x * b.x + b.y * b.y + b.z * b.z + b.w * b.w;
#pragma unroll
    for (int off = 32; off > 0; off >>= 1) ss += __shfl_xor(ss, off, 64);
    const float iv = 1.0f / fmaxf(sqrtf(ss), 1e-12f);
    if (t == 0) inv[row] = iv;
    ushort4 ua, ub;
    ua.x = f2b(a.x * iv); ua.y = f2b(a.y * iv); ua.z = f2b(a.z * iv); ua.w = f2b(a.w * iv);
    ub.x = f2b(b.x * iv); ub.y = f2b(b.y * iv); ub.z = f2b(b.z * iv); ub.w = f2b(b.w * iv);
    ((ushort4*)(Xb + (size_t)row * D))[t] = ua;
    ((ushort4*)(Xb + (size_t)row * D))[t + 64] = ub;
}

// ---------------- Kernel 2: bf16 MFMA GEMM -> bf16 C (in d_ws) -----------
// Main loop identical to R4 (proven). Epilogue now restages the C tile
// through LDS (xor-swizzled, 16B-aligned pitch) and writes 256-B-granule
// coalesced rows instead of 2-B scattered stores.
__global__ __launch_bounds__(256) void gemm_kernel(const unsigned short* __restrict__ Xb,
                                                   unsigned short* __restrict__ Cout) {
    __shared__ unsigned short smem[128 * CPITCH];  // 34.8 KB; reused: Al|Bl then Cs
    unsigned short* Al = smem;                     // 128*APAD = 5120 shorts
    unsigned short* Bl = smem + 128 * APAD;        // next 5120 shorts
    const int tid = threadIdx.x;
    const int w = tid >> 6;
    const int lane = tid & 63;
    const int wr = w >> 1, wc = w & 1;
    const int i0 = blockIdx.y * 128, j0 = blockIdx.x * 128;

    const int r0 = tid >> 2;
    const int q = tid & 3;

    floatx4 acc[4][4];
#pragma unroll
    for (int ti = 0; ti < 4; ++ti)
#pragma unroll
        for (int tj = 0; tj < 4; ++tj) acc[ti][tj] = (floatx4){0.f, 0.f, 0.f, 0.f};

    const unsigned short* gA0 = Xb + (size_t)(i0 + r0) * D + q * 8;
    const unsigned short* gA1 = Xb + (size_t)(i0 + r0 + 64) * D + q * 8;
    const unsigned short* gB0 = Xb + (size_t)(j0 + r0) * D + q * 8;
    const unsigned short* gB1 = Xb + (size_t)(j0 + r0 + 64) * D + q * 8;

    int4 pa0 = *(const int4*)gA0;
    int4 pa1 = *(const int4*)gA1;
    int4 pb0 = *(const int4*)gB0;
    int4 pb1 = *(const int4*)gB1;

    const int lrow = lane & 15;
    const int lq = lane >> 4;
    const unsigned short* aF = Al + (size_t)(wr * 64 + lrow) * APAD + lq * 8;
    const unsigned short* bF = Bl + (size_t)(wc * 64 + lrow) * APAD + lq * 8;

    for (int kc = 0; kc < D / 32; ++kc) {
        __syncthreads();
        *(int4*)&Al[r0 * APAD + q * 8] = pa0;
        *(int4*)&Al[(r0 + 64) * APAD + q * 8] = pa1;
        *(int4*)&Bl[r0 * APAD + q * 8] = pb0;
        *(int4*)&Bl[(r0 + 64) * APAD + q * 8] = pb1;
        __syncthreads();
        if (kc < D / 32 - 1) {
            const int o = (kc + 1) * 32;
            pa0 = *(const int4*)(gA0 + o);
            pa1 = *(const int4*)(gA1 + o);
            pb0 = *(const int4*)(gB0 + o);
            pb1 = *(const int4*)(gB1 + o);
        }
        short8 af[4], bf[4];
#pragma unroll
        for (int ti = 0; ti < 4; ++ti) af[ti] = *(const short8*)(aF + ti * 16 * APAD);
#pragma unroll
        for (int tj = 0; tj < 4; ++tj) bf[tj] = *(const short8*)(bF + tj * 16 * APAD);
#pragma unroll
        for (int ti = 0; ti < 4; ++ti)
#pragma unroll
            for (int tj = 0; tj < 4; ++tj)
                acc[ti][tj] = __builtin_amdgcn_mfma_f32_16x16x32_bf16(af[ti], bf[tj],
                                                                      acc[ti][tj], 0, 0, 0);
    }

    // ---- epilogue: LDS restage -> coalesced writes ----
    __syncthreads();  // all frag reads done; smem now reused as Cs
    unsigned short* Cs = smem;
#pragma unroll
    for (int ti = 0; ti < 4; ++ti)
#pragma unroll
        for (int tj = 0; tj < 4; ++tj)
#pragma unroll
            for (int reg = 0; reg < 4; ++reg) {
                const int rowl = wr * 64 + ti * 16 + lq * 4 + reg;
                const int coll = wc * 64 + tj * 16 + lrow;
                // xor-swizzle the 8-short chunk id by (row&7): conflict-free read
                Cs[rowl * CPITCH + (coll ^ ((rowl & 7) << 3))] = f2b(acc[ti][tj][reg]);
            }
    __syncthreads();
#pragma unroll
    for (int p = 0; p < 8; ++p) {
        const int id = p * 256 + tid;   // 2048 16-B chunks: 128 rows x 16
        const int row = id >> 4;
        const int c = id & 15;
        const int cc = c ^ (row & 7);
        const int4 v = *(const int4*)&Cs[row * CPITCH + cc * 8];
        *(int4*)&Cout[(size_t)(i0 + row) * N + j0 + c * 8] = v;
    }
}

// ---------------- Kernel 3: scan C + rescore + softmax + zero + scatter --
// Block b: 4 waves, wave w owns result row 4b+w end-to-end. C lives in
// d_ws so output writes never alias C reads of other blocks.
__global__ __launch_bounds__(256) void scanfin_kernel(const unsigned short* __restrict__ C,
                                                      const float* __restrict__ X,
                                                      const float* __restrict__ inv,
                                                      float* __restrict__ out) {
    __shared__ int scnt[4];
    __shared__ int sci[4][CCAP];
    const int tid = threadIdx.x;
    const int w = tid >> 6;
    const int lane = tid & 63;
    const int row = (int)blockIdx.x * 4 + w;
    const unsigned short* cr = C + (size_t)row * N;
    if (lane == 0) scnt[w] = 0;
    __syncthreads();

    float tv[1][5];
    int tix[1][5];
#pragma unroll
    for (int s = 0; s < 5; ++s) { tv[0][s] = -1e30f; tix[0][s] = 0x7fffffff; }

    // pass 1: per-lane top-5 with max-prune fast path
    for (int it = 0; it < N / 256; ++it) {
        const ushort4 u = *(const ushort4*)(cr + it * 256 + lane * 4);
        const float v0 = b2f(u.x), v1 = b2f(u.y), v2 = b2f(u.z), v3 = b2f(u.w);
        const float vmax = fmaxf(fmaxf(v0, v1), fmaxf(v2, v3));
        if (vmax >= tv[0][4]) {
            const int jb = it * 256 + lane * 4;
            INS(tv, tix, 0, v0, jb);
            INS(tv, tix, 0, v1, jb + 1);
            INS(tv, tix, 0, v2, jb + 2);
            INS(tv, tix, 0, v3, jb + 3);
        }
    }
    // butterfly merge -> exact top-5 of approx row (converges on all lanes)
#pragma unroll
    for (int m = 1; m < 64; m <<= 1) {
        float p0 = __shfl_xor(tv[0][0], m, 64), p1 = __shfl_xor(tv[0][1], m, 64);
        float p2 = __shfl_xor(tv[0][2], m, 64), p3 = __shfl_xor(tv[0][3], m, 64);
        float p4 = __shfl_xor(tv[0][4], m, 64);
        int q0 = __shfl_xor(tix[0][0], m, 64), q1 = __shfl_xor(tix[0][1], m, 64);
        int q2 = __shfl_xor(tix[0][2], m, 64), q3 = __shfl_xor(tix[0][3], m, 64);
        int q4 = __shfl_xor(tix[0][4], m, 64);
        INS(tv, tix, 0, p0, q0);
        INS(tv, tix, 0, p1, q1);
        INS(tv, tix, 0, p2, q2);
        INS(tv, tix, 0, p3, q3);
        INS(tv, tix, 0, p4, q4);
    }
    const float thr = tv[0][4] - MARGIN;

    // pass 2 (L2-hot): emit margin superset into LDS
    for (int it = 0; it < N / 256; ++it) {
        const ushort4 u = *(const ushort4*)(cr + it * 256 + lane * 4);
        const int jb = it * 256 + lane * 4;
#pragma unroll
        for (int c = 0; c < 4; ++c) {
            const float v = b2f(c == 0 ? u.x : (c == 1 ? u.y : (c == 2 ? u.z : u.w)));
            if (v >= thr) {
                const int p = atomicAdd(&scnt[w], 1);
                if (p < CCAP) sci[w][p] = jb + c;
            }
        }
    }
    __syncthreads();
    int nc = scnt[w];
    if (nc > CCAP) nc = CCAP;

    // fp32 rescore (wave-cooperative), exact lexicographic top-5
    const float4* xr = (const float4*)(X + (size_t)row * D);
    const float4 xa = xr[lane * 2];
    const float4 xb = xr[lane * 2 + 1];
    const float myinv = inv[row];
    float ev[1][5];
    int ei[1][5];
#pragma unroll
    for (int s = 0; s < 5; ++s) { ev[0][s] = -1e30f; ei[0][s] = 0x7fffffff; }
    for (int c = 0; c < nc; ++c) {
        const int cj = sci[w][c];
        const float4* yr = (const float4*)(X + (size_t)cj * D);
        const float4 ya = yr[lane * 2];
        const float4 yb = yr[lane * 2 + 1];
        float p = xa.x * ya.x + xa.y * ya.y + xa.z * ya.z + xa.w * ya.w +
                  xb.x * yb.x + xb.y * yb.y + xb.z * yb.z + xb.w * yb.w;
#pragma unroll
        for (int off = 32; off > 0; off >>= 1) p += __shfl_xor(p, off, 64);
        const float val = p * myinv * inv[cj];
        INS(ev, ei, 0, val, cj);  // wave-uniform
    }

    // zero this wave's output row (32 KB), then scatter after barrier
    float4* orow = (float4*)(out + (size_t)row * N);
    const float4 z = make_float4(0.f, 0.f, 0.f, 0.f);
    for (int it = lane; it < N / 4; it += 64) orow[it] = z;
    __syncthreads();  // zeros drained (waitcnt before barrier) before scatter

    if (lane == 0) {
        float e[KSEL];
        float sum = 0.f;
#pragma unroll
        for (int s = 0; s < KSEL; ++s) {
            e[s] = expf((ev[0][s] - ev[0][0]) * TEMP_INV);
            sum += e[s];
        }
        const float invs = 1.0f / sum;
#pragma unroll
        for (int s = 0; s < KSEL; ++s) {
            const int ix = ei[0][s];
            if (ix >= 0 && ix < N) out[(size_t)row * N + ix] = e[s] * invs;
        }
    }
}

extern "C" void kernel_launch(void* const* d_in, const int* in_sizes, int n_in,
                              void* d_out, int out_size, void* d_ws, size_t ws_size,
                              hipStream_t stream) {
    const float* X = (const float*)d_in[0];
    float* out = (float*)d_out;
    // ws (1 GiB): Xb bf16 [8 MB] | inv [32 KB] | C bf16 [128 MB @ +16 MB]
    unsigned short* Xb = (unsigned short*)d_ws;
    float* inv = (float*)(Xb + (size_t)N * D);
    unsigned short* C = (unsigned short*)((char*)d_ws + (16u << 20));

    hipLaunchKernelGGL(prep_kernel, dim3(N), dim3(64), 0, stream, X, Xb, inv);
    hipLaunchKernelGGL(gemm_kernel, dim3(N / 128, N / 128), dim3(256), 0, stream, Xb, C);
    hipLaunchKernelGGL(scanfin_kernel, dim3(N / 4), dim3(256), 0, stream, C, X, inv, out);
}

// Round 6
// 448.418 us; speedup vs baseline: 1.0565x; 1.0565x over previous
//
#include <hip/hip_runtime.h>
#include <math.h>

#define N 8192
#define D 512
#define KSEL 5
#define TEMP_INV 10.0f
#define MARGIN 0.012f
#define CCAP 48
#define BK 64
#define CPITCH 136  // epilogue C-stage pitch in shorts (R5-proven)

using short8 = __attribute__((ext_vector_type(8))) short;
using floatx4 = __attribute__((ext_vector_type(4))) float;

// Lexicographic top-5 insert: (value desc, index asc) — matches lax.top_k.
#define INS(TV, TIX, RI, VV, JJ)                                                     \
  {                                                                                  \
    const float _v = (VV);                                                           \
    const int _j = (JJ);                                                             \
    const bool _b4 = (_v > TV[RI][4]) || (_v == TV[RI][4] && _j < TIX[RI][4]);       \
    if (_b4) {                                                                       \
      const bool _b0 = (_v > TV[RI][0]) || (_v == TV[RI][0] && _j < TIX[RI][0]);     \
      const bool _b1 = (_v > TV[RI][1]) || (_v == TV[RI][1] && _j < TIX[RI][1]);     \
      const bool _b2 = (_v > TV[RI][2]) || (_v == TV[RI][2] && _j < TIX[RI][2]);     \
      const bool _b3 = (_v > TV[RI][3]) || (_v == TV[RI][3] && _j < TIX[RI][3]);     \
      TV[RI][4] = _b3 ? TV[RI][3] : _v;                                              \
      TIX[RI][4] = _b3 ? TIX[RI][3] : _j;                                            \
      TV[RI][3] = _b2 ? TV[RI][2] : (_b3 ? _v : TV[RI][3]);                          \
      TIX[RI][3] = _b2 ? TIX[RI][2] : (_b3 ? _j : TIX[RI][3]);                       \
      TV[RI][2] = _b1 ? TV[RI][1] : (_b2 ? _v : TV[RI][2]);                          \
      TIX[RI][2] = _b1 ? TIX[RI][1] : (_b2 ? _j : TIX[RI][2]);                       \
      TV[RI][1] = _b0 ? TV[RI][0] : (_b1 ? _v : TV[RI][1]);                          \
      TIX[RI][1] = _b0 ? TIX[RI][0] : (_b1 ? _j : TIX[RI][1]);                       \
      TV[RI][0] = _b0 ? _v : TV[RI][0];                                              \
      TIX[RI][0] = _b0 ? _j : TIX[RI][0];                                            \
    }                                                                                \
  }

__device__ inline unsigned short f2b(float f) {  // fp32 -> bf16 RNE
    unsigned int u = __float_as_uint(f);
    unsigned int r = (u + 0x7FFFu + ((u >> 16) & 1u)) >> 16;
    return (unsigned short)r;
}
__device__ inline float b2f(unsigned short u) {
    return __uint_as_float(((unsigned int)u) << 16);
}

// 16-B direct global->LDS (DMA; LDS dest = wave-uniform base + lane*16)
__device__ inline void gload_lds16(const unsigned short* g, unsigned short* l) {
    __builtin_amdgcn_global_load_lds((__attribute__((address_space(1))) void*)g,
                                     (__attribute__((address_space(3))) void*)l, 16, 0, 0);
}

// ---------------- Kernel 1: norms + bf16 normalized rows -----------------
__global__ __launch_bounds__(64) void prep_kernel(const float* __restrict__ X,
                                                  unsigned short* __restrict__ Xb,
                                                  float* __restrict__ inv) {
    const int row = blockIdx.x;
    const int t = threadIdx.x;
    const float4* xr = (const float4*)(X + (size_t)row * D);
    const float4 a = xr[t];
    const float4 b = xr[t + 64];
    float ss = a.x * a.x + a.y * a.y + a.z * a.z + a.w * a.w +
               b.x * b.x + b.y * b.y + b.z * b.z + b.w * b.w;
#pragma unroll
    for (int off = 32; off > 0; off >>= 1) ss += __shfl_xor(ss, off, 64);
    const float iv = 1.0f / fmaxf(sqrtf(ss), 1e-12f);
    if (t == 0) inv[row] = iv;
    ushort4 ua, ub;
    ua.x = f2b(a.x * iv); ua.y = f2b(a.y * iv); ua.z = f2b(a.z * iv); ua.w = f2b(a.w * iv);
    ub.x = f2b(b.x * iv); ub.y = f2b(b.y * iv); ub.z = f2b(b.z * iv); ub.w = f2b(b.w * iv);
    ((ushort4*)(Xb + (size_t)row * D))[t] = ua;
    ((ushort4*)(Xb + (size_t)row * D))[t + 64] = ub;
}

// ---------------- Kernel 2: bf16 MFMA GEMM (m97-style K-loop) ------------
// 128x128 tile, BK=64, single-buffer 2-barrier loop, global_load_lds w=16.
// LDS chunk slot for (row, kq) = row*8 + (kq ^ (row&7)); the swizzle lives
// in the global-side lane->chunk map (LDS side must stay lane-linear).
// Frag reads then hit each bank-quad exactly 2x (free, m136).
__global__ __launch_bounds__(256) void gemm_kernel(const unsigned short* __restrict__ Xb,
                                                   unsigned short* __restrict__ Cout) {
    __shared__ unsigned short smem[128 * CPITCH];  // 34.8 KB (A|B 32 KB, then Cs)
    unsigned short* Asm = smem;          // 8192 shorts = 16 KB (1024 slots)
    unsigned short* Bsm = smem + 8192;   // 16 KB
    const int tid = threadIdx.x;
    const int w = tid >> 6;
    const int lane = tid & 63;
    const int wr = w >> 1, wc = w & 1;
    const int i0 = blockIdx.y * 128, j0 = blockIdx.x * 128;

    floatx4 acc[4][4];
#pragma unroll
    for (int ti = 0; ti < 4; ++ti)
#pragma unroll
        for (int tj = 0; tj < 4; ++tj) acc[ti][tj] = (floatx4){0.f, 0.f, 0.f, 0.f};

    // staging: 1024 slots per matrix, 4 per thread; slot = p*256 + tid
    const unsigned short* gA[4];
    const unsigned short* gB[4];
    unsigned short* lA[4];
    unsigned short* lB[4];
#pragma unroll
    for (int p = 0; p < 4; ++p) {
        const int slot = p * 256 + tid;
        const int row = slot >> 3;
        const int kq = (slot & 7) ^ (row & 7);  // global chunk for this slot
        gA[p] = Xb + (size_t)(i0 + row) * D + kq * 8;
        gB[p] = Xb + (size_t)(j0 + row) * D + kq * 8;
        lA[p] = Asm + slot * 8;
        lB[p] = Bsm + slot * 8;
    }

    // fragment read addressing
    const int r = lane & 15;
    const int q = lane >> 4;
    const int aRow0 = wr * 64 + r;   // + ti*16
    const int bRow0 = wc * 64 + r;   // + tj*16
    const int rx = r & 7;

    // issue loads for kc=0
#pragma unroll
    for (int p = 0; p < 4; ++p) {
        gload_lds16(gA[p], lA[p]);
        gload_lds16(gB[p], lB[p]);
    }

    for (int kc = 0; kc < D / BK; ++kc) {
        __syncthreads();  // vmcnt(0): chunk kc landed in LDS
        short8 af[2][4], bf[2][4];
#pragma unroll
        for (int t = 0; t < 2; ++t)
#pragma unroll
            for (int ti = 0; ti < 4; ++ti) {
                af[t][ti] = *(const short8*)(Asm +
                    ((aRow0 + ti * 16) * 8 + ((t * 4 + q) ^ rx)) * 8);
                bf[t][ti] = *(const short8*)(Bsm +
                    ((bRow0 + ti * 16) * 8 + ((t * 4 + q) ^ rx)) * 8);
            }
        __syncthreads();  // lgkmcnt(0): all waves' frag reads done
        if (kc < D / BK - 1) {
            const int o = (kc + 1) * BK;
#pragma unroll
            for (int p = 0; p < 4; ++p) {
                gload_lds16(gA[p] + o, lA[p]);
                gload_lds16(gB[p] + o, lB[p]);
            }
        }
#pragma unroll
        for (int t = 0; t < 2; ++t)
#pragma unroll
            for (int ti = 0; ti < 4; ++ti)
#pragma unroll
                for (int tj = 0; tj < 4; ++tj)
                    acc[ti][tj] = __builtin_amdgcn_mfma_f32_16x16x32_bf16(
                        af[t][ti], bf[t][tj], acc[ti][tj], 0, 0, 0);
    }

    // ---- epilogue: LDS restage -> coalesced bf16 writes (R5-proven) ----
    __syncthreads();
    unsigned short* Cs = smem;
    const int lrow = r, lq = q;
#pragma unroll
    for (int ti = 0; ti < 4; ++ti)
#pragma unroll
        for (int tj = 0; tj < 4; ++tj)
#pragma unroll
            for (int reg = 0; reg < 4; ++reg) {
                const int rowl = wr * 64 + ti * 16 + lq * 4 + reg;
                const int coll = wc * 64 + tj * 16 + lrow;
                Cs[rowl * CPITCH + (coll ^ ((rowl & 7) << 3))] = f2b(acc[ti][tj][reg]);
            }
    __syncthreads();
#pragma unroll
    for (int p = 0; p < 8; ++p) {
        const int id = p * 256 + tid;
        const int row = id >> 4;
        const int c = id & 15;
        const int cc = c ^ (row & 7);
        const int4 v = *(const int4*)&Cs[row * CPITCH + cc * 8];
        *(int4*)&Cout[(size_t)(i0 + row) * N + j0 + c * 8] = v;
    }
}

// ---------------- Kernel 3: scan C + rescore + softmax + zero + scatter --
__global__ __launch_bounds__(256) void scanfin_kernel(const unsigned short* __restrict__ C,
                                                      const float* __restrict__ X,
                                                      const float* __restrict__ inv,
                                                      float* __restrict__ out) {
    __shared__ int scnt[4];
    __shared__ int sci[4][CCAP];
    const int tid = threadIdx.x;
    const int w = tid >> 6;
    const int lane = tid & 63;
    const int row = (int)blockIdx.x * 4 + w;
    const unsigned short* cr = C + (size_t)row * N;
    if (lane == 0) scnt[w] = 0;
    __syncthreads();

    float tv[1][5];
    int tix[1][5];
#pragma unroll
    for (int s = 0; s < 5; ++s) { tv[0][s] = -1e30f; tix[0][s] = 0x7fffffff; }

    for (int it = 0; it < N / 256; ++it) {
        const ushort4 u = *(const ushort4*)(cr + it * 256 + lane * 4);
        const float v0 = b2f(u.x), v1 = b2f(u.y), v2 = b2f(u.z), v3 = b2f(u.w);
        const float vmax = fmaxf(fmaxf(v0, v1), fmaxf(v2, v3));
        if (vmax >= tv[0][4]) {
            const int jb = it * 256 + lane * 4;
            INS(tv, tix, 0, v0, jb);
            INS(tv, tix, 0, v1, jb + 1);
            INS(tv, tix, 0, v2, jb + 2);
            INS(tv, tix, 0, v3, jb + 3);
        }
    }
#pragma unroll
    for (int m = 1; m < 64; m <<= 1) {
        float p0 = __shfl_xor(tv[0][0], m, 64), p1 = __shfl_xor(tv[0][1], m, 64);
        float p2 = __shfl_xor(tv[0][2], m, 64), p3 = __shfl_xor(tv[0][3], m, 64);
        float p4 = __shfl_xor(tv[0][4], m, 64);
        int q0 = __shfl_xor(tix[0][0], m, 64), q1 = __shfl_xor(tix[0][1], m, 64);
        int q2 = __shfl_xor(tix[0][2], m, 64), q3 = __shfl_xor(tix[0][3], m, 64);
        int q4 = __shfl_xor(tix[0][4], m, 64);
        INS(tv, tix, 0, p0, q0);
        INS(tv, tix, 0, p1, q1);
        INS(tv, tix, 0, p2, q2);
        INS(tv, tix, 0, p3, q3);
        INS(tv, tix, 0, p4, q4);
    }
    const float thr = tv[0][4] - MARGIN;

    for (int it = 0; it < N / 256; ++it) {
        const ushort4 u = *(const ushort4*)(cr + it * 256 + lane * 4);
        const int jb = it * 256 + lane * 4;
#pragma unroll
        for (int c = 0; c < 4; ++c) {
            const float v = b2f(c == 0 ? u.x : (c == 1 ? u.y : (c == 2 ? u.z : u.w)));
            if (v >= thr) {
                const int p = atomicAdd(&scnt[w], 1);
                if (p < CCAP) sci[w][p] = jb + c;
            }
        }
    }
    __syncthreads();
    int nc = scnt[w];
    if (nc > CCAP) nc = CCAP;

    const float4* xr = (const float4*)(X + (size_t)row * D);
    const float4 xa = xr[lane * 2];
    const float4 xb = xr[lane * 2 + 1];
    const float myinv = inv[row];
    float ev[1][5];
    int ei[1][5];
#pragma unroll
    for (int s = 0; s < 5; ++s) { ev[0][s] = -1e30f; ei[0][s] = 0x7fffffff; }
    for (int c = 0; c < nc; ++c) {
        const int cj = sci[w][c];
        const float4* yr = (const float4*)(X + (size_t)cj * D);
        const float4 ya = yr[lane * 2];
        const float4 yb = yr[lane * 2 + 1];
        float p = xa.x * ya.x + xa.y * ya.y + xa.z * ya.z + xa.w * ya.w +
                  xb.x * yb.x + xb.y * yb.y + xb.z * yb.z + xb.w * yb.w;
#pragma unroll
        for (int off = 32; off > 0; off >>= 1) p += __shfl_xor(p, off, 64);
        const float val = p * myinv * inv[cj];
        INS(ev, ei, 0, val, cj);
    }

    float4* orow = (float4*)(out + (size_t)row * N);
    const float4 z = make_float4(0.f, 0.f, 0.f, 0.f);
    for (int it = lane; it < N / 4; it += 64) orow[it] = z;
    __syncthreads();

    if (lane == 0) {
        float e[KSEL];
        float sum = 0.f;
#pragma unroll
        for (int s = 0; s < KSEL; ++s) {
            e[s] = expf((ev[0][s] - ev[0][0]) * TEMP_INV);
            sum += e[s];
        }
        const float invs = 1.0f / sum;
#pragma unroll
        for (int s = 0; s < KSEL; ++s) {
            const int ix = ei[0][s];
            if (ix >= 0 && ix < N) out[(size_t)row * N + ix] = e[s] * invs;
        }
    }
}

extern "C" void kernel_launch(void* const* d_in, const int* in_sizes, int n_in,
                              void* d_out, int out_size, void* d_ws, size_t ws_size,
                              hipStream_t stream) {
    const float* X = (const float*)d_in[0];
    float* out = (float*)d_out;
    // ws (1 GiB): Xb bf16 [8 MB] | inv [32 KB] | C bf16 [128 MB @ +16 MB]
    unsigned short* Xb = (unsigned short*)d_ws;
    float* inv = (float*)(Xb + (size_t)N * D);
    unsigned short* C = (unsigned short*)((char*)d_ws + (16u << 20));

    hipLaunchKernelGGL(prep_kernel, dim3(N), dim3(64), 0, stream, X, Xb, inv);
    hipLaunchKernelGGL(gemm_kernel, dim3(N / 128, N / 128), dim3(256), 0, stream, Xb, C);
    hipLaunchKernelGGL(scanfin_kernel, dim3(N / 4), dim3(256), 0, stream, C, X, inv, out);
}

// Round 7
// 401.955 us; speedup vs baseline: 1.1786x; 1.1156x over previous
//
#include <hip/hip_runtime.h>
#include <math.h>

#define N 8192
#define D 512
#define KSEL 5
#define TEMP_INV 10.0f
#define MARGIN 0.012f
#define CCAP 64
#define BK 64
#define CPITCH 136  // epilogue C-stage pitch in shorts (R5-proven)
#define NSTRIP 128  // 64-col strips per row

using short8 = __attribute__((ext_vector_type(8))) short;
using floatx4 = __attribute__((ext_vector_type(4))) float;

// Lexicographic top-5 insert: (value desc, index asc) — matches lax.top_k.
#define INS(TV, TIX, RI, VV, JJ)                                                     \
  {                                                                                  \
    const float _v = (VV);                                                           \
    const int _j = (JJ);                                                             \
    const bool _b4 = (_v > TV[RI][4]) || (_v == TV[RI][4] && _j < TIX[RI][4]);       \
    if (_b4) {                                                                       \
      const bool _b0 = (_v > TV[RI][0]) || (_v == TV[RI][0] && _j < TIX[RI][0]);     \
      const bool _b1 = (_v > TV[RI][1]) || (_v == TV[RI][1] && _j < TIX[RI][1]);     \
      const bool _b2 = (_v > TV[RI][2]) || (_v == TV[RI][2] && _j < TIX[RI][2]);     \
      const bool _b3 = (_v > TV[RI][3]) || (_v == TV[RI][3] && _j < TIX[RI][3]);     \
      TV[RI][4] = _b3 ? TV[RI][3] : _v;                                              \
      TIX[RI][4] = _b3 ? TIX[RI][3] : _j;                                            \
      TV[RI][3] = _b2 ? TV[RI][2] : (_b3 ? _v : TV[RI][3]);                          \
      TIX[RI][3] = _b2 ? TIX[RI][2] : (_b3 ? _j : TIX[RI][3]);                       \
      TV[RI][2] = _b1 ? TV[RI][1] : (_b2 ? _v : TV[RI][2]);                          \
      TIX[RI][2] = _b1 ? TIX[RI][1] : (_b2 ? _j : TIX[RI][2]);                       \
      TV[RI][1] = _b0 ? TV[RI][0] : (_b1 ? _v : TV[RI][1]);                          \
      TIX[RI][1] = _b0 ? TIX[RI][0] : (_b1 ? _j : TIX[RI][1]);                       \
      TV[RI][0] = _b0 ? _v : TV[RI][0];                                              \
      TIX[RI][0] = _b0 ? _j : TIX[RI][0];                                            \
    }                                                                                \
  }

__device__ inline unsigned short f2b(float f) {  // fp32 -> bf16 RNE (monotone)
    unsigned int u = __float_as_uint(f);
    unsigned int r = (u + 0x7FFFu + ((u >> 16) & 1u)) >> 16;
    return (unsigned short)r;
}
__device__ inline float b2f(unsigned short u) {
    return __uint_as_float(((unsigned int)u) << 16);
}

__device__ inline void gload_lds16(const unsigned short* g, unsigned short* l) {
    __builtin_amdgcn_global_load_lds((__attribute__((address_space(1))) void*)g,
                                     (__attribute__((address_space(3))) void*)l, 16, 0, 0);
}

// ---------------- Kernel 1: norms + bf16 normalized rows -----------------
__global__ __launch_bounds__(64) void prep_kernel(const float* __restrict__ X,
                                                  unsigned short* __restrict__ Xb,
                                                  float* __restrict__ inv) {
    const int row = blockIdx.x;
    const int t = threadIdx.x;
    const float4* xr = (const float4*)(X + (size_t)row * D);
    const float4 a = xr[t];
    const float4 b = xr[t + 64];
    float ss = a.x * a.x + a.y * a.y + a.z * a.z + a.w * a.w +
               b.x * b.x + b.y * b.y + b.z * b.z + b.w * b.w;
#pragma unroll
    for (int off = 32; off > 0; off >>= 1) ss += __shfl_xor(ss, off, 64);
    const float iv = 1.0f / fmaxf(sqrtf(ss), 1e-12f);
    if (t == 0) inv[row] = iv;
    ushort4 ua, ub;
    ua.x = f2b(a.x * iv); ua.y = f2b(a.y * iv); ua.z = f2b(a.z * iv); ua.w = f2b(a.w * iv);
    ub.x = f2b(b.x * iv); ub.y = f2b(b.y * iv); ub.z = f2b(b.z * iv); ub.w = f2b(b.w * iv);
    ((ushort4*)(Xb + (size_t)row * D))[t] = ua;
    ((ushort4*)(Xb + (size_t)row * D))[t + 64] = ub;
}

// ---------------- Kernel 2: bf16 MFMA GEMM + per-strip row maxima --------
__global__ __launch_bounds__(256) void gemm_kernel(const unsigned short* __restrict__ Xb,
                                                   unsigned short* __restrict__ Cout,
                                                   unsigned short* __restrict__ rowmaxG) {
    __shared__ unsigned short smem[128 * CPITCH];  // 34.8 KB (A|B 32 KB, then Cs)
    unsigned short* Asm = smem;
    unsigned short* Bsm = smem + 8192;
    const int tid = threadIdx.x;
    const int w = tid >> 6;
    const int lane = tid & 63;
    const int wr = w >> 1, wc = w & 1;
    const int i0 = blockIdx.y * 128, j0 = blockIdx.x * 128;

    floatx4 acc[4][4];
#pragma unroll
    for (int ti = 0; ti < 4; ++ti)
#pragma unroll
        for (int tj = 0; tj < 4; ++tj) acc[ti][tj] = (floatx4){0.f, 0.f, 0.f, 0.f};

    const unsigned short* gA[4];
    const unsigned short* gB[4];
    unsigned short* lA[4];
    unsigned short* lB[4];
#pragma unroll
    for (int p = 0; p < 4; ++p) {
        const int slot = p * 256 + tid;
        const int row = slot >> 3;
        const int kq = (slot & 7) ^ (row & 7);
        gA[p] = Xb + (size_t)(i0 + row) * D + kq * 8;
        gB[p] = Xb + (size_t)(j0 + row) * D + kq * 8;
        lA[p] = Asm + slot * 8;
        lB[p] = Bsm + slot * 8;
    }

    const int r = lane & 15;
    const int q = lane >> 4;
    const int aRow0 = wr * 64 + r;
    const int bRow0 = wc * 64 + r;
    const int rx = r & 7;

#pragma unroll
    for (int p = 0; p < 4; ++p) {
        gload_lds16(gA[p], lA[p]);
        gload_lds16(gB[p], lB[p]);
    }

    for (int kc = 0; kc < D / BK; ++kc) {
        __syncthreads();
        short8 af[2][4], bf[2][4];
#pragma unroll
        for (int t = 0; t < 2; ++t)
#pragma unroll
            for (int ti = 0; ti < 4; ++ti) {
                af[t][ti] = *(const short8*)(Asm +
                    ((aRow0 + ti * 16) * 8 + ((t * 4 + q) ^ rx)) * 8);
                bf[t][ti] = *(const short8*)(Bsm +
                    ((bRow0 + ti * 16) * 8 + ((t * 4 + q) ^ rx)) * 8);
            }
        __syncthreads();
        if (kc < D / BK - 1) {
            const int o = (kc + 1) * BK;
#pragma unroll
            for (int p = 0; p < 4; ++p) {
                gload_lds16(gA[p] + o, lA[p]);
                gload_lds16(gB[p] + o, lB[p]);
            }
        }
#pragma unroll
        for (int t = 0; t < 2; ++t)
#pragma unroll
            for (int ti = 0; ti < 4; ++ti)
#pragma unroll
                for (int tj = 0; tj < 4; ++tj)
                    acc[ti][tj] = __builtin_amdgcn_mfma_f32_16x16x32_bf16(
                        af[t][ti], bf[t][tj], acc[ti][tj], 0, 0, 0);
    }

    // ---- per-(row, 64-col-strip) maxima (feeds scanfin's threshold) ----
    {
        float rmax[16];
#pragma unroll
        for (int ti = 0; ti < 4; ++ti)
#pragma unroll
            for (int reg = 0; reg < 4; ++reg) {
                const float m0 = fmaxf(acc[ti][0][reg], acc[ti][1][reg]);
                const float m1 = fmaxf(acc[ti][2][reg], acc[ti][3][reg]);
                rmax[ti * 4 + reg] = fmaxf(m0, m1);
            }
#pragma unroll
        for (int k = 0; k < 16; ++k)
#pragma unroll
            for (int m = 1; m < 16; m <<= 1)
                rmax[k] = fmaxf(rmax[k], __shfl_xor(rmax[k], m, 64));
        if (r == 0) {
            const int strip = (int)blockIdx.x * 2 + wc;
#pragma unroll
            for (int ti = 0; ti < 4; ++ti)
#pragma unroll
                for (int reg = 0; reg < 4; ++reg)
                    rowmaxG[(size_t)(i0 + wr * 64 + ti * 16 + q * 4 + reg) * NSTRIP +
                            strip] = f2b(rmax[ti * 4 + reg]);
        }
    }

    // ---- epilogue: LDS restage -> coalesced bf16 C writes (R5-proven) ----
    __syncthreads();
    unsigned short* Cs = smem;
#pragma unroll
    for (int ti = 0; ti < 4; ++ti)
#pragma unroll
        for (int tj = 0; tj < 4; ++tj)
#pragma unroll
            for (int reg = 0; reg < 4; ++reg) {
                const int rowl = wr * 64 + ti * 16 + q * 4 + reg;
                const int coll = wc * 64 + tj * 16 + r;
                Cs[rowl * CPITCH + (coll ^ ((rowl & 7) << 3))] = f2b(acc[ti][tj][reg]);
            }
    __syncthreads();
#pragma unroll
    for (int p = 0; p < 8; ++p) {
        const int id = p * 256 + tid;
        const int row = id >> 4;
        const int c = id & 15;
        const int cc = c ^ (row & 7);
        const int4 v = *(const int4*)&Cs[row * CPITCH + cc * 8];
        *(int4*)&Cout[(size_t)(i0 + row) * N + j0 + c * 8] = v;
    }
}

// ---------------- Kernel 3: stripmax-guided candidates + rescore + out ---
// Wave w of block b owns row 4b+w end-to-end. No full-C scan: only strips
// whose max >= m5 - MARGIN are read (~10 of 128).
__global__ __launch_bounds__(256) void scanfin_kernel(const unsigned short* __restrict__ C,
                                                      const unsigned short* __restrict__ rowmaxG,
                                                      const float* __restrict__ X,
                                                      const float* __restrict__ inv,
                                                      float* __restrict__ out) {
    __shared__ int acnt[4];
    __shared__ int alist[4][NSTRIP];
    __shared__ int scnt[4];
    __shared__ int sci[4][CCAP];
    const int tid = threadIdx.x;
    const int w = tid >> 6;
    const int lane = tid & 63;
    const int row = (int)blockIdx.x * 4 + w;
    const unsigned short* cr = C + (size_t)row * N;
    if (lane == 0) { acnt[w] = 0; scnt[w] = 0; }

    // strip maxima (128 bf16, 2 per lane)
    const ushort2 su = *(const ushort2*)(rowmaxG + (size_t)row * NSTRIP + lane * 2);
    const float s0v = b2f(su.x), s1v = b2f(su.y);

    // m5 = 5th-largest strip-max via 5 rounds of wave-max + remove-one
    float a = s0v, b = s1v;
    float m5 = -1e30f;
#pragma unroll
    for (int s = 0; s < 5; ++s) {
        float mx = fmaxf(a, b);
#pragma unroll
        for (int m = 32; m > 0; m >>= 1) mx = fmaxf(mx, __shfl_xor(mx, m, 64));
        m5 = mx;
        const unsigned long long msk = __ballot(a == mx || b == mx);
        const int first = __ffsll(msk) - 1;
        if (lane == first) {
            if (a == mx) a = -1e30f;
            else b = -1e30f;
        }
    }
    const float thr = m5 - MARGIN;

    // compact active strips (per-wave LDS, no cross-wave use)
    if (s0v >= thr) { const int p = atomicAdd(&acnt[w], 1); alist[w][p] = lane * 2; }
    if (s1v >= thr) { const int p = atomicAdd(&acnt[w], 1); alist[w][p] = lane * 2 + 1; }
    const int na = acnt[w];

    // emission: 2 strips per pass, half-wave each; strip = 64 cols = 128 B
    for (int g = 0; g < na; g += 2) {
        const int s = (lane < 32) ? alist[w][g] : ((g + 1 < na) ? alist[w][g + 1] : -1);
        if (s >= 0) {
            const int jb = s * 64 + (lane & 31) * 2;
            const ushort2 u = *(const ushort2*)(cr + jb);
            const float v0 = b2f(u.x), v1 = b2f(u.y);
            if (v0 >= thr) { const int p = atomicAdd(&scnt[w], 1); if (p < CCAP) sci[w][p] = jb; }
            if (v1 >= thr) { const int p = atomicAdd(&scnt[w], 1); if (p < CCAP) sci[w][p] = jb + 1; }
        }
    }
    int nc = scnt[w];
    if (nc > CCAP) nc = CCAP;

    // fp32 rescore (wave-cooperative), exact lexicographic top-5
    const float4* xr = (const float4*)(X + (size_t)row * D);
    const float4 xa = xr[lane * 2];
    const float4 xb = xr[lane * 2 + 1];
    const float myinv = inv[row];
    float ev[1][5];
    int ei[1][5];
#pragma unroll
    for (int s = 0; s < 5; ++s) { ev[0][s] = -1e30f; ei[0][s] = 0x7fffffff; }
    for (int c = 0; c < nc; ++c) {
        const int cj = sci[w][c];
        const float4* yr = (const float4*)(X + (size_t)cj * D);
        const float4 ya = yr[lane * 2];
        const float4 yb = yr[lane * 2 + 1];
        float p = xa.x * ya.x + xa.y * ya.y + xa.z * ya.z + xa.w * ya.w +
                  xb.x * yb.x + xb.y * yb.y + xb.z * yb.z + xb.w * yb.w;
#pragma unroll
        for (int off = 32; off > 0; off >>= 1) p += __shfl_xor(p, off, 64);
        const float val = p * myinv * inv[cj];
        INS(ev, ei, 0, val, cj);
    }

    // zero this wave's output row, then scatter after barrier
    float4* orow = (float4*)(out + (size_t)row * N);
    const float4 z = make_float4(0.f, 0.f, 0.f, 0.f);
    for (int it = lane; it < N / 4; it += 64) orow[it] = z;
    __syncthreads();

    if (lane == 0) {
        float e[KSEL];
        float sum = 0.f;
#pragma unroll
        for (int s = 0; s < KSEL; ++s) {
            e[s] = expf((ev[0][s] - ev[0][0]) * TEMP_INV);
            sum += e[s];
        }
        const float invs = 1.0f / sum;
#pragma unroll
        for (int s = 0; s < KSEL; ++s) {
            const int ix = ei[0][s];
            if (ix >= 0 && ix < N) out[(size_t)row * N + ix] = e[s] * invs;
        }
    }
}

extern "C" void kernel_launch(void* const* d_in, const int* in_sizes, int n_in,
                              void* d_out, int out_size, void* d_ws, size_t ws_size,
                              hipStream_t stream) {
    const float* X = (const float*)d_in[0];
    float* out = (float*)d_out;
    // ws (1 GiB): Xb bf16 [8 MB] | inv [32 KB] | rowmax bf16 [2 MB] | C bf16 [128 MB @ +16 MB]
    unsigned short* Xb = (unsigned short*)d_ws;
    float* inv = (float*)(Xb + (size_t)N * D);
    unsigned short* rowmaxG = (unsigned short*)(inv + N);
    unsigned short* C = (unsigned short*)((char*)d_ws + (16u << 20));

    hipLaunchKernelGGL(prep_kernel, dim3(N), dim3(64), 0, stream, X, Xb, inv);
    hipLaunchKernelGGL(gemm_kernel, dim3(N / 128, N / 128), dim3(256), 0, stream, Xb, C,
                       rowmaxG);
    hipLaunchKernelGGL(scanfin_kernel, dim3(N / 4), dim3(256), 0, stream, C, rowmaxG, X, inv,
                       out);
}

// Round 8
// 395.172 us; speedup vs baseline: 1.1988x; 1.0172x over previous
//
#include <hip/hip_runtime.h>
#include <math.h>

#define N 8192
#define D 512
#define KSEL 5
#define TEMP_INV 10.0f
#define MARGIN 0.012f
#define CCAP 64
#define BK 64
#define CPITCH 136  // epilogue C-stage pitch in shorts (R5-proven)
#define NSTRIP 128  // 64-col strips per row
#define NTILE 64
#define NBLK (NTILE * (NTILE + 1) / 2)  // 2080 upper-triangle tiles

using short8 = __attribute__((ext_vector_type(8))) short;
using floatx4 = __attribute__((ext_vector_type(4))) float;

// Lexicographic top-5 insert: (value desc, index asc) — matches lax.top_k.
#define INS(TV, TIX, RI, VV, JJ)                                                     \
  {                                                                                  \
    const float _v = (VV);                                                           \
    const int _j = (JJ);                                                             \
    const bool _b4 = (_v > TV[RI][4]) || (_v == TV[RI][4] && _j < TIX[RI][4]);       \
    if (_b4) {                                                                       \
      const bool _b0 = (_v > TV[RI][0]) || (_v == TV[RI][0] && _j < TIX[RI][0]);     \
      const bool _b1 = (_v > TV[RI][1]) || (_v == TV[RI][1] && _j < TIX[RI][1]);     \
      const bool _b2 = (_v > TV[RI][2]) || (_v == TV[RI][2] && _j < TIX[RI][2]);     \
      const bool _b3 = (_v > TV[RI][3]) || (_v == TV[RI][3] && _j < TIX[RI][3]);     \
      TV[RI][4] = _b3 ? TV[RI][3] : _v;                                              \
      TIX[RI][4] = _b3 ? TIX[RI][3] : _j;                                            \
      TV[RI][3] = _b2 ? TV[RI][2] : (_b3 ? _v : TV[RI][3]);                          \
      TIX[RI][3] = _b2 ? TIX[RI][2] : (_b3 ? _j : TIX[RI][3]);                       \
      TV[RI][2] = _b1 ? TV[RI][1] : (_b2 ? _v : TV[RI][2]);                          \
      TIX[RI][2] = _b1 ? TIX[RI][1] : (_b2 ? _j : TIX[RI][2]);                       \
      TV[RI][1] = _b0 ? TV[RI][0] : (_b1 ? _v : TV[RI][1]);                          \
      TIX[RI][1] = _b0 ? TIX[RI][0] : (_b1 ? _j : TIX[RI][1]);                       \
      TV[RI][0] = _b0 ? _v : TV[RI][0];                                              \
      TIX[RI][0] = _b0 ? _j : TIX[RI][0];                                            \
    }                                                                                \
  }

__device__ inline unsigned short f2b(float f) {  // fp32 -> bf16 RNE (monotone)
    unsigned int u = __float_as_uint(f);
    unsigned int r = (u + 0x7FFFu + ((u >> 16) & 1u)) >> 16;
    return (unsigned short)r;
}
__device__ inline float b2f(unsigned short u) {
    return __uint_as_float(((unsigned int)u) << 16);
}

__device__ inline void gload_lds16(const unsigned short* g, unsigned short* l) {
    __builtin_amdgcn_global_load_lds((__attribute__((address_space(1))) void*)g,
                                     (__attribute__((address_space(3))) void*)l, 16, 0, 0);
}

// ---------------- Kernel 1: norms + bf16 normalized rows -----------------
__global__ __launch_bounds__(64) void prep_kernel(const float* __restrict__ X,
                                                  unsigned short* __restrict__ Xb,
                                                  float* __restrict__ inv) {
    const int row = blockIdx.x;
    const int t = threadIdx.x;
    const float4* xr = (const float4*)(X + (size_t)row * D);
    const float4 a = xr[t];
    const float4 b = xr[t + 64];
    float ss = a.x * a.x + a.y * a.y + a.z * a.z + a.w * a.w +
               b.x * b.x + b.y * b.y + b.z * b.z + b.w * b.w;
#pragma unroll
    for (int off = 32; off > 0; off >>= 1) ss += __shfl_xor(ss, off, 64);
    const float iv = 1.0f / fmaxf(sqrtf(ss), 1e-12f);
    if (t == 0) inv[row] = iv;
    ushort4 ua, ub;
    ua.x = f2b(a.x * iv); ua.y = f2b(a.y * iv); ua.z = f2b(a.z * iv); ua.w = f2b(a.w * iv);
    ub.x = f2b(b.x * iv); ub.y = f2b(b.y * iv); ub.z = f2b(b.z * iv); ub.w = f2b(b.w * iv);
    ((ushort4*)(Xb + (size_t)row * D))[t] = ua;
    ((ushort4*)(Xb + (size_t)row * D))[t + 64] = ub;
}

// ---------------- Kernel 2: symmetric bf16 MFMA GEMM ---------------------
// Upper-triangle tile (tib <= tjb) per block; writes tile + mirror, and
// strip-maxes for both row-sets. K-loop identical to R6/R7 (proven).
__global__ __launch_bounds__(256) void gemm_kernel(const unsigned short* __restrict__ Xb,
                                                   unsigned short* __restrict__ Cout,
                                                   unsigned short* __restrict__ rowmaxG) {
    __shared__ unsigned short smem[128 * CPITCH];  // 34.8 KB (A|B 32 KB, then Cs)
    unsigned short* Asm = smem;
    unsigned short* Bsm = smem + 8192;
    const int tid = threadIdx.x;
    const int w = tid >> 6;
    const int lane = tid & 63;
    const int wr = w >> 1, wc = w & 1;

    // decode upper-triangle pair: off(ti) = ti*(129-ti)/2
    const int t = (int)blockIdx.x;
    int tib = (int)((129.0 - sqrt(129.0 * 129.0 - 8.0 * (double)t)) * 0.5);
    while ((tib + 1) * (129 - (tib + 1)) / 2 <= t) ++tib;
    while (tib * (129 - tib) / 2 > t) --tib;
    const int tjb = tib + (t - tib * (129 - tib) / 2);
    const int i0 = tib * 128, j0 = tjb * 128;

    floatx4 acc[4][4];
#pragma unroll
    for (int ti = 0; ti < 4; ++ti)
#pragma unroll
        for (int tj = 0; tj < 4; ++tj) acc[ti][tj] = (floatx4){0.f, 0.f, 0.f, 0.f};

    const unsigned short* gA[4];
    const unsigned short* gB[4];
    unsigned short* lA[4];
    unsigned short* lB[4];
#pragma unroll
    for (int p = 0; p < 4; ++p) {
        const int slot = p * 256 + tid;
        const int row = slot >> 3;
        const int kq = (slot & 7) ^ (row & 7);
        gA[p] = Xb + (size_t)(i0 + row) * D + kq * 8;
        gB[p] = Xb + (size_t)(j0 + row) * D + kq * 8;
        lA[p] = Asm + slot * 8;
        lB[p] = Bsm + slot * 8;
    }

    const int r = lane & 15;
    const int q = lane >> 4;
    const int aRow0 = wr * 64 + r;
    const int bRow0 = wc * 64 + r;
    const int rx = r & 7;

#pragma unroll
    for (int p = 0; p < 4; ++p) {
        gload_lds16(gA[p], lA[p]);
        gload_lds16(gB[p], lB[p]);
    }

    for (int kc = 0; kc < D / BK; ++kc) {
        __syncthreads();
        short8 af[2][4], bf[2][4];
#pragma unroll
        for (int tt = 0; tt < 2; ++tt)
#pragma unroll
            for (int ti = 0; ti < 4; ++ti) {
                af[tt][ti] = *(const short8*)(Asm +
                    ((aRow0 + ti * 16) * 8 + ((tt * 4 + q) ^ rx)) * 8);
                bf[tt][ti] = *(const short8*)(Bsm +
                    ((bRow0 + ti * 16) * 8 + ((tt * 4 + q) ^ rx)) * 8);
            }
        __syncthreads();
        if (kc < D / BK - 1) {
            const int o = (kc + 1) * BK;
#pragma unroll
            for (int p = 0; p < 4; ++p) {
                gload_lds16(gA[p] + o, lA[p]);
                gload_lds16(gB[p] + o, lB[p]);
            }
        }
#pragma unroll
        for (int tt = 0; tt < 2; ++tt)
#pragma unroll
            for (int ti = 0; ti < 4; ++ti)
#pragma unroll
                for (int tj = 0; tj < 4; ++tj)
                    acc[ti][tj] = __builtin_amdgcn_mfma_f32_16x16x32_bf16(
                        af[tt][ti], bf[tt][tj], acc[ti][tj], 0, 0, 0);
    }

    // ---- A-side strip maxima: rows i0.., strip tjb*2 + wc ----
    {
        float rmax[16];
#pragma unroll
        for (int ti = 0; ti < 4; ++ti)
#pragma unroll
            for (int reg = 0; reg < 4; ++reg) {
                const float m0 = fmaxf(acc[ti][0][reg], acc[ti][1][reg]);
                const float m1 = fmaxf(acc[ti][2][reg], acc[ti][3][reg]);
                rmax[ti * 4 + reg] = fmaxf(m0, m1);
            }
#pragma unroll
        for (int k = 0; k < 16; ++k)
#pragma unroll
            for (int m = 1; m < 16; m <<= 1)
                rmax[k] = fmaxf(rmax[k], __shfl_xor(rmax[k], m, 64));
        if (r == 0) {
            const int strip = tjb * 2 + wc;
#pragma unroll
            for (int ti = 0; ti < 4; ++ti)
#pragma unroll
                for (int reg = 0; reg < 4; ++reg)
                    rowmaxG[(size_t)(i0 + wr * 64 + ti * 16 + q * 4 + reg) * NSTRIP +
                            strip] = f2b(rmax[ti * 4 + reg]);
        }
    }

    // ---- B-side strip maxima (mirror): rows j0.., strip tib*2 + wr ----
    if (tib != tjb) {
        float cmax[4];
#pragma unroll
        for (int tj = 0; tj < 4; ++tj) {
            float m = -1e30f;
#pragma unroll
            for (int ti = 0; ti < 4; ++ti)
#pragma unroll
                for (int reg = 0; reg < 4; ++reg) m = fmaxf(m, acc[ti][tj][reg]);
            m = fmaxf(m, __shfl_xor(m, 16, 64));
            m = fmaxf(m, __shfl_xor(m, 32, 64));
            cmax[tj] = m;
        }
        if (q == 0) {
#pragma unroll
            for (int tj = 0; tj < 4; ++tj)
                rowmaxG[(size_t)(j0 + wc * 64 + tj * 16 + r) * NSTRIP + tib * 2 + wr] =
                    f2b(cmax[tj]);
        }
    }

    // ---- epilogue: LDS restage -> coalesced bf16 C writes ----
    __syncthreads();
    unsigned short* Cs = smem;
#pragma unroll
    for (int ti = 0; ti < 4; ++ti)
#pragma unroll
        for (int tj = 0; tj < 4; ++tj)
#pragma unroll
            for (int reg = 0; reg < 4; ++reg) {
                const int rowl = wr * 64 + ti * 16 + q * 4 + reg;
                const int coll = wc * 64 + tj * 16 + r;
                Cs[rowl * CPITCH + (coll ^ ((rowl & 7) << 3))] = f2b(acc[ti][tj][reg]);
            }
    __syncthreads();
#pragma unroll
    for (int p = 0; p < 8; ++p) {
        const int id = p * 256 + tid;
        const int rw = id >> 4;
        const int c = id & 15;
        const int cc = c ^ (rw & 7);
        const int4 v = *(const int4*)&Cs[rw * CPITCH + cc * 8];
        *(int4*)&Cout[(size_t)(i0 + rw) * N + j0 + c * 8] = v;
    }

    // ---- mirror tile: C[j0..][i0..] = tile^T ----
    if (tib != tjb) {
        __syncthreads();  // all Cs reads above complete
#pragma unroll
        for (int ti = 0; ti < 4; ++ti)
#pragma unroll
            for (int tj = 0; tj < 4; ++tj)
#pragma unroll
                for (int reg = 0; reg < 4; ++reg) {
                    const int rowl = wr * 64 + ti * 16 + q * 4 + reg;
                    const int coll = wc * 64 + tj * 16 + r;
                    Cs[coll * CPITCH + (rowl ^ ((coll & 7) << 3))] = f2b(acc[ti][tj][reg]);
                }
        __syncthreads();
#pragma unroll
        for (int p = 0; p < 8; ++p) {
            const int id = p * 256 + tid;
            const int rw = id >> 4;
            const int c = id & 15;
            const int cc = c ^ (rw & 7);
            const int4 v = *(const int4*)&Cs[rw * CPITCH + cc * 8];
            *(int4*)&Cout[(size_t)(j0 + rw) * N + i0 + c * 8] = v;
        }
    }
}

// ---------------- Kernel 3: stripmax-guided candidates + rescore + out ---
__global__ __launch_bounds__(256) void scanfin_kernel(const unsigned short* __restrict__ C,
                                                      const unsigned short* __restrict__ rowmaxG,
                                                      const float* __restrict__ X,
                                                      const float* __restrict__ inv,
                                                      float* __restrict__ out) {
    __shared__ int acnt[4];
    __shared__ int alist[4][NSTRIP];
    __shared__ int scnt[4];
    __shared__ int sci[4][CCAP];
    const int tid = threadIdx.x;
    const int w = tid >> 6;
    const int lane = tid & 63;
    const int row = (int)blockIdx.x * 4 + w;
    const unsigned short* cr = C + (size_t)row * N;
    if (lane == 0) { acnt[w] = 0; scnt[w] = 0; }

    const ushort2 su = *(const ushort2*)(rowmaxG + (size_t)row * NSTRIP + lane * 2);
    const float s0v = b2f(su.x), s1v = b2f(su.y);

    float a = s0v, b = s1v;
    float m5 = -1e30f;
#pragma unroll
    for (int s = 0; s < 5; ++s) {
        float mx = fmaxf(a, b);
#pragma unroll
        for (int m = 32; m > 0; m >>= 1) mx = fmaxf(mx, __shfl_xor(mx, m, 64));
        m5 = mx;
        const unsigned long long msk = __ballot(a == mx || b == mx);
        const int first = __ffsll(msk) - 1;
        if (lane == first) {
            if (a == mx) a = -1e30f;
            else b = -1e30f;
        }
    }
    const float thr = m5 - MARGIN;

    if (s0v >= thr) { const int p = atomicAdd(&acnt[w], 1); alist[w][p] = lane * 2; }
    if (s1v >= thr) { const int p = atomicAdd(&acnt[w], 1); alist[w][p] = lane * 2 + 1; }
    const int na = acnt[w];

    for (int g = 0; g < na; g += 2) {
        const int s = (lane < 32) ? alist[w][g] : ((g + 1 < na) ? alist[w][g + 1] : -1);
        if (s >= 0) {
            const int jb = s * 64 + (lane & 31) * 2;
            const ushort2 u = *(const ushort2*)(cr + jb);
            const float v0 = b2f(u.x), v1 = b2f(u.y);
            if (v0 >= thr) { const int p = atomicAdd(&scnt[w], 1); if (p < CCAP) sci[w][p] = jb; }
            if (v1 >= thr) { const int p = atomicAdd(&scnt[w], 1); if (p < CCAP) sci[w][p] = jb + 1; }
        }
    }
    int nc = scnt[w];
    if (nc > CCAP) nc = CCAP;

    const float4* xr = (const float4*)(X + (size_t)row * D);
    const float4 xa = xr[lane * 2];
    const float4 xb = xr[lane * 2 + 1];
    const float myinv = inv[row];
    float ev[1][5];
    int ei[1][5];
#pragma unroll
    for (int s = 0; s < 5; ++s) { ev[0][s] = -1e30f; ei[0][s] = 0x7fffffff; }
    for (int c = 0; c < nc; ++c) {
        const int cj = sci[w][c];
        const float4* yr = (const float4*)(X + (size_t)cj * D);
        const float4 ya = yr[lane * 2];
        const float4 yb = yr[lane * 2 + 1];
        float p = xa.x * ya.x + xa.y * ya.y + xa.z * ya.z + xa.w * ya.w +
                  xb.x * yb.x + xb.y * yb.y + xb.z * yb.z + xb.w * yb.w;
#pragma unroll
        for (int off = 32; off > 0; off >>= 1) p += __shfl_xor(p, off, 64);
        const float val = p * myinv * inv[cj];
        INS(ev, ei, 0, val, cj);
    }

    float4* orow = (float4*)(out + (size_t)row * N);
    const float4 z = make_float4(0.f, 0.f, 0.f, 0.f);
    for (int it = lane; it < N / 4; it += 64) orow[it] = z;
    __syncthreads();

    if (lane == 0) {
        float e[KSEL];
        float sum = 0.f;
#pragma unroll
        for (int s = 0; s < KSEL; ++s) {
            e[s] = expf((ev[0][s] - ev[0][0]) * TEMP_INV);
            sum += e[s];
        }
        const float invs = 1.0f / sum;
#pragma unroll
        for (int s = 0; s < KSEL; ++s) {
            const int ix = ei[0][s];
            if (ix >= 0 && ix < N) out[(size_t)row * N + ix] = e[s] * invs;
        }
    }
}

extern "C" void kernel_launch(void* const* d_in, const int* in_sizes, int n_in,
                              void* d_out, int out_size, void* d_ws, size_t ws_size,
                              hipStream_t stream) {
    const float* X = (const float*)d_in[0];
    float* out = (float*)d_out;
    // ws (1 GiB): Xb bf16 [8 MB] | inv [32 KB] | rowmax bf16 [2 MB] | C bf16 [128 MB @ +16 MB]
    unsigned short* Xb = (unsigned short*)d_ws;
    float* inv = (float*)(Xb + (size_t)N * D);
    unsigned short* rowmaxG = (unsigned short*)(inv + N);
    unsigned short* C = (unsigned short*)((char*)d_ws + (16u << 20));

    hipLaunchKernelGGL(prep_kernel, dim3(N), dim3(64), 0, stream, X, Xb, inv);
    hipLaunchKernelGGL(gemm_kernel, dim3(NBLK), dim3(256), 0, stream, Xb, C, rowmaxG);
    hipLaunchKernelGGL(scanfin_kernel, dim3(N / 4), dim3(256), 0, stream, C, rowmaxG, X, inv,
                       out);
}